// Round 1
// baseline (137.164 us; speedup 1.0000x reference)
//
#include <hip/hip_runtime.h>

#define FILLV (-10000.0f)

__device__ __forceinline__ float4 f4max(float4 a, float4 b) {
    return make_float4(fmaxf(a.x, b.x), fmaxf(a.y, b.y),
                       fmaxf(a.z, b.z), fmaxf(a.w, b.w));
}

// Kernel 1: per (batch, L-segment) partial max over valid rows only.
// Block = 256 threads, each thread owns one float4 column (D = 1024 floats = 256 float4).
__global__ void feasel_partial_kernel(const float* __restrict__ feat,
                                      const int* __restrict__ lengths,
                                      float* __restrict__ part,
                                      int L, int DV, int segLen) {
    const int b = blockIdx.x;
    const int s = blockIdx.y;
    const int S = gridDim.y;
    const int t = threadIdx.x;          // 0..DV-1

    const int len = lengths[b];
    const int l0 = s * segLen;
    const int l1 = min(l0 + segLen, len);

    const float4* __restrict__ base =
        reinterpret_cast<const float4*>(feat) + (size_t)b * L * DV;

    float4 a0 = make_float4(FILLV, FILLV, FILLV, FILLV);
    float4 a1 = a0, a2 = a0, a3 = a0;

    int l = l0;
    for (; l + 4 <= l1; l += 4) {
        float4 v0 = base[(size_t)(l + 0) * DV + t];
        float4 v1 = base[(size_t)(l + 1) * DV + t];
        float4 v2 = base[(size_t)(l + 2) * DV + t];
        float4 v3 = base[(size_t)(l + 3) * DV + t];
        a0 = f4max(a0, v0);
        a1 = f4max(a1, v1);
        a2 = f4max(a2, v2);
        a3 = f4max(a3, v3);
    }
    for (; l < l1; ++l) {
        a0 = f4max(a0, base[(size_t)l * DV + t]);
    }
    a0 = f4max(f4max(a0, a1), f4max(a2, a3));

    reinterpret_cast<float4*>(part)[((size_t)b * S + s) * DV + t] = a0;
}

// Kernel 2: reduce S partials per batch, apply len==0 -> 0 rule.
__global__ void feasel_reduce_kernel(const float* __restrict__ part,
                                     const int* __restrict__ lengths,
                                     float* __restrict__ out,
                                     int DV, int S) {
    const int b = blockIdx.x;
    const int t = threadIdx.x;

    const float4* __restrict__ p =
        reinterpret_cast<const float4*>(part) + (size_t)b * S * DV;

    float4 acc = make_float4(FILLV, FILLV, FILLV, FILLV);
    for (int s = 0; s < S; ++s)
        acc = f4max(acc, p[(size_t)s * DV + t]);

    if (lengths[b] <= 0)
        acc = make_float4(0.f, 0.f, 0.f, 0.f);

    reinterpret_cast<float4*>(out)[(size_t)b * DV + t] = acc;
}

// Fallback if workspace is too small for even one partial slice per batch:
// one block per batch does the whole reduction directly into d_out.
__global__ void feasel_direct_kernel(const float* __restrict__ feat,
                                     const int* __restrict__ lengths,
                                     float* __restrict__ out,
                                     int L, int DV) {
    const int b = blockIdx.x;
    const int t = threadIdx.x;
    const int len = lengths[b];

    const float4* __restrict__ base =
        reinterpret_cast<const float4*>(feat) + (size_t)b * L * DV;

    float4 a0 = make_float4(FILLV, FILLV, FILLV, FILLV);
    float4 a1 = a0, a2 = a0, a3 = a0;

    int l = 0;
    for (; l + 4 <= len; l += 4) {
        a0 = f4max(a0, base[(size_t)(l + 0) * DV + t]);
        a1 = f4max(a1, base[(size_t)(l + 1) * DV + t]);
        a2 = f4max(a2, base[(size_t)(l + 2) * DV + t]);
        a3 = f4max(a3, base[(size_t)(l + 3) * DV + t]);
    }
    for (; l < len; ++l)
        a0 = f4max(a0, base[(size_t)l * DV + t]);

    a0 = f4max(f4max(a0, a1), f4max(a2, a3));
    if (len <= 0)
        a0 = make_float4(0.f, 0.f, 0.f, 0.f);

    reinterpret_cast<float4*>(out)[(size_t)b * DV + t] = a0;
}

extern "C" void kernel_launch(void* const* d_in, const int* in_sizes, int n_in,
                              void* d_out, int out_size, void* d_ws, size_t ws_size,
                              hipStream_t stream) {
    const float* feat    = (const float*)d_in[0];   // [B, L, D] fp32
    const int*   lengths = (const int*)d_in[1];     // [B] int32
    float*       out     = (float*)d_out;           // [B, D] fp32

    const int B  = in_sizes[1];
    const int D  = out_size / B;                    // 1024
    const int DV = D / 4;                           // 256 float4 per row
    const int L  = in_sizes[0] / (B * D);           // 4096

    // Pick number of L-segments per batch that fits in workspace (partial is B*S*D fp32).
    int S = 32;
    while (S > 1 && (size_t)B * S * D * sizeof(float) > ws_size) S >>= 1;

    if ((size_t)B * S * D * sizeof(float) <= ws_size) {
        float* part = (float*)d_ws;
        const int segLen = (L + S - 1) / S;
        dim3 grid1(B, S);
        feasel_partial_kernel<<<grid1, DV, 0, stream>>>(feat, lengths, part, L, DV, segLen);
        feasel_reduce_kernel<<<B, DV, 0, stream>>>(part, lengths, out, DV, S);
    } else {
        feasel_direct_kernel<<<B, DV, 0, stream>>>(feat, lengths, out, L, DV);
    }
}

// Round 2
// 116.319 us; speedup vs baseline: 1.1792x; 1.1792x over previous
//
#include <hip/hip_runtime.h>

#define FILLV (-10000.0f)

typedef __attribute__((ext_vector_type(4))) float f32x4;

__device__ __forceinline__ f32x4 vmax4(f32x4 a, f32x4 b) {
    f32x4 r;
    r.x = fmaxf(a.x, b.x);
    r.y = fmaxf(a.y, b.y);
    r.z = fmaxf(a.z, b.z);
    r.w = fmaxf(a.w, b.w);
    return r;
}

__device__ __forceinline__ f32x4 ntload(const f32x4* p) {
    return __builtin_nontemporal_load(p);
}

__device__ __forceinline__ f32x4 fillv4() {
    f32x4 v = {FILLV, FILLV, FILLV, FILLV};
    return v;
}

// Kernel 1: per (batch, L-segment) partial max over valid rows only.
// Block = DV threads (256), each thread owns one float4 column.
// ALL blocks (even fully-masked ones) write their partial slot so the
// workspace is fully defined every call (harness poisons ws once).
__global__ void feasel_partial_kernel(const float* __restrict__ feat,
                                      const int* __restrict__ lengths,
                                      float* __restrict__ part,
                                      int L, int DV, int segLen) {
    const int b = blockIdx.x;
    const int s = blockIdx.y;
    const int S = gridDim.y;
    const int t = threadIdx.x;

    const int len = lengths[b];
    const int l0 = s * segLen;
    const int l1 = min(min(l0 + segLen, len), L);

    const f32x4* __restrict__ p =
        reinterpret_cast<const f32x4*>(feat) + (size_t)b * L * DV + (size_t)l0 * DV + t;

    f32x4 a0 = fillv4(), a1 = fillv4(), a2 = fillv4(), a3 = fillv4();
    f32x4 a4 = fillv4(), a5 = fillv4(), a6 = fillv4(), a7 = fillv4();

    int l = l0;
    for (; l + 8 <= l1; l += 8) {
        f32x4 v0 = ntload(p + 0 * (size_t)DV);
        f32x4 v1 = ntload(p + 1 * (size_t)DV);
        f32x4 v2 = ntload(p + 2 * (size_t)DV);
        f32x4 v3 = ntload(p + 3 * (size_t)DV);
        f32x4 v4 = ntload(p + 4 * (size_t)DV);
        f32x4 v5 = ntload(p + 5 * (size_t)DV);
        f32x4 v6 = ntload(p + 6 * (size_t)DV);
        f32x4 v7 = ntload(p + 7 * (size_t)DV);
        a0 = vmax4(a0, v0);
        a1 = vmax4(a1, v1);
        a2 = vmax4(a2, v2);
        a3 = vmax4(a3, v3);
        a4 = vmax4(a4, v4);
        a5 = vmax4(a5, v5);
        a6 = vmax4(a6, v6);
        a7 = vmax4(a7, v7);
        p += 8 * (size_t)DV;
    }
    for (; l < l1; ++l) {
        a0 = vmax4(a0, ntload(p));
        p += DV;
    }

    a0 = vmax4(a0, a1);
    a2 = vmax4(a2, a3);
    a4 = vmax4(a4, a5);
    a6 = vmax4(a6, a7);
    a0 = vmax4(vmax4(a0, a2), vmax4(a4, a6));

    reinterpret_cast<f32x4*>(part)[((size_t)b * S + s) * DV + t] = a0;
}

// Kernel 2: reduce S partials per batch, apply len==0 -> 0 rule.
// Grid (B, ceil(DV/64)) x 64 threads: one wave per block, spread over CUs.
__global__ void feasel_reduce_kernel(const float* __restrict__ part,
                                     const int* __restrict__ lengths,
                                     float* __restrict__ out,
                                     int DV, int S) {
    const int b = blockIdx.x;
    const int c = blockIdx.y * 64 + threadIdx.x;
    if (c >= DV) return;

    const f32x4* __restrict__ p =
        reinterpret_cast<const f32x4*>(part) + (size_t)b * S * DV + c;

    f32x4 a0 = fillv4(), a1 = fillv4(), a2 = fillv4(), a3 = fillv4();
    int s = 0;
    for (; s + 4 <= S; s += 4) {
        a0 = vmax4(a0, p[(size_t)(s + 0) * DV]);
        a1 = vmax4(a1, p[(size_t)(s + 1) * DV]);
        a2 = vmax4(a2, p[(size_t)(s + 2) * DV]);
        a3 = vmax4(a3, p[(size_t)(s + 3) * DV]);
    }
    for (; s < S; ++s)
        a0 = vmax4(a0, p[(size_t)s * DV]);
    a0 = vmax4(vmax4(a0, a1), vmax4(a2, a3));

    if (lengths[b] <= 0) {
        f32x4 z = {0.f, 0.f, 0.f, 0.f};
        a0 = z;
    }
    reinterpret_cast<f32x4*>(out)[(size_t)b * DV + c] = a0;
}

// Fallback if workspace is too small: one block per batch, direct.
__global__ void feasel_direct_kernel(const float* __restrict__ feat,
                                     const int* __restrict__ lengths,
                                     float* __restrict__ out,
                                     int L, int DV) {
    const int b = blockIdx.x;
    const int t = threadIdx.x;
    const int len = min(lengths[b], L);

    const f32x4* __restrict__ p =
        reinterpret_cast<const f32x4*>(feat) + (size_t)b * L * DV + t;

    f32x4 a0 = fillv4(), a1 = fillv4(), a2 = fillv4(), a3 = fillv4();
    int l = 0;
    for (; l + 4 <= len; l += 4) {
        a0 = vmax4(a0, ntload(p + 0 * (size_t)DV));
        a1 = vmax4(a1, ntload(p + 1 * (size_t)DV));
        a2 = vmax4(a2, ntload(p + 2 * (size_t)DV));
        a3 = vmax4(a3, ntload(p + 3 * (size_t)DV));
        p += 4 * (size_t)DV;
    }
    for (; l < len; ++l) {
        a0 = vmax4(a0, ntload(p));
        p += DV;
    }
    a0 = vmax4(vmax4(a0, a1), vmax4(a2, a3));
    if (len <= 0) {
        f32x4 z = {0.f, 0.f, 0.f, 0.f};
        a0 = z;
    }
    reinterpret_cast<f32x4*>(out)[(size_t)b * DV + t] = a0;
}

extern "C" void kernel_launch(void* const* d_in, const int* in_sizes, int n_in,
                              void* d_out, int out_size, void* d_ws, size_t ws_size,
                              hipStream_t stream) {
    const float* feat    = (const float*)d_in[0];   // [B, L, D] fp32
    const int*   lengths = (const int*)d_in[1];     // [B] int32
    float*       out     = (float*)d_out;           // [B, D] fp32

    const int B  = in_sizes[1];
    const int D  = out_size / B;                    // 1024
    const int DV = D / 4;                           // 256 float4 per row
    const int L  = in_sizes[0] / (B * D);           // 4096

    // Number of L-segments per batch, sized to fit the partial buffer in ws.
    int S = 64;
    while (S > 1 && (size_t)B * S * D * sizeof(float) > ws_size) S >>= 1;

    if ((size_t)B * S * D * sizeof(float) <= ws_size) {
        float* part = (float*)d_ws;
        const int segLen = (L + S - 1) / S;
        dim3 grid1(B, S);
        feasel_partial_kernel<<<grid1, DV, 0, stream>>>(feat, lengths, part, L, DV, segLen);
        dim3 grid2(B, (DV + 63) / 64);
        feasel_reduce_kernel<<<grid2, 64, 0, stream>>>(part, lengths, out, DV, S);
    } else {
        feasel_direct_kernel<<<B, DV, 0, stream>>>(feat, lengths, out, L, DV);
    }
}

// Round 4
// 105.495 us; speedup vs baseline: 1.3002x; 1.1026x over previous
//
#include <hip/hip_runtime.h>

#define FILLV (-10000.0f)

typedef __attribute__((ext_vector_type(4))) float f32x4;

__device__ __forceinline__ f32x4 vmax4(f32x4 a, f32x4 b) {
    f32x4 r;
    r.x = fmaxf(a.x, b.x);
    r.y = fmaxf(a.y, b.y);
    r.z = fmaxf(a.z, b.z);
    r.w = fmaxf(a.w, b.w);
    return r;
}

__device__ __forceinline__ f32x4 ntload(const f32x4* p) {
    return __builtin_nontemporal_load(p);
}

__device__ __forceinline__ f32x4 fillv4() {
    f32x4 v = {FILLV, FILLV, FILLV, FILLV};
    return v;
}

// ---------------------------------------------------------------------------
// Kernel 1: self-scheduling balanced partial max.
// Fixed grid of NBLK blocks; each block rebuilds the (b, seg)-item prefix map
// from `lengths` in shared memory (no cross-kernel worklist handoff), then
// grid-strides the items. Item = seg rows of one batch -> partial slot (b,s).
// ---------------------------------------------------------------------------
__global__ __launch_bounds__(256, 4)
void feasel_partial_kernel(const float* __restrict__ feat,
                           const int* __restrict__ lengths,
                           float* __restrict__ part,
                           int B, int L, int DV, int seg, int S) {
    __shared__ int off[1025];            // prefix offsets, supports B <= 1024
    const int t = threadIdx.x;

    // number of valid segments per batch -> off[] prefix sum
    for (int b = t; b < B; b += blockDim.x) {
        int len = lengths[b];
        len = len < 0 ? 0 : (len > L ? L : len);
        int n = (len + seg - 1) / seg;
        if (n > S) n = S;
        off[b + 1] = n;
    }
    __syncthreads();
    if (t == 0) {
        off[0] = 0;
        for (int b = 0; b < B; ++b) off[b + 1] += off[b];   // serial over B (small)
    }
    __syncthreads();
    const int W = off[B];

    for (int i = blockIdx.x; i < W; i += gridDim.x) {
        // largest b with off[b] <= i  (6 broadcast shared reads for B=64)
        int lo = 0, hi = B;
        while (hi - lo > 1) {
            int m = (lo + hi) >> 1;
            if (off[m] <= i) lo = m; else hi = m;
        }
        const int b = lo;
        const int s = i - off[lo];

        int len = lengths[b];
        len = len > L ? L : len;
        const int l0 = s * seg;
        const int l1 = min(l0 + seg, len);

        const f32x4* __restrict__ p =
            reinterpret_cast<const f32x4*>(feat) + (size_t)b * L * DV + (size_t)l0 * DV + t;

        f32x4 a0 = fillv4(), a1 = fillv4(), a2 = fillv4(), a3 = fillv4();

        int l = l0;
        for (; l + 8 <= l1; l += 8) {
            f32x4 v0 = ntload(p + 0 * (size_t)DV);
            f32x4 v1 = ntload(p + 1 * (size_t)DV);
            f32x4 v2 = ntload(p + 2 * (size_t)DV);
            f32x4 v3 = ntload(p + 3 * (size_t)DV);
            f32x4 v4 = ntload(p + 4 * (size_t)DV);
            f32x4 v5 = ntload(p + 5 * (size_t)DV);
            f32x4 v6 = ntload(p + 6 * (size_t)DV);
            f32x4 v7 = ntload(p + 7 * (size_t)DV);
            a0 = vmax4(a0, vmax4(v0, v4));
            a1 = vmax4(a1, vmax4(v1, v5));
            a2 = vmax4(a2, vmax4(v2, v6));
            a3 = vmax4(a3, vmax4(v3, v7));
            p += 8 * (size_t)DV;
        }
        for (; l < l1; ++l) {
            a0 = vmax4(a0, ntload(p));
            p += DV;
        }
        a0 = vmax4(vmax4(a0, a1), vmax4(a2, a3));

        reinterpret_cast<f32x4*>(part)[((size_t)b * S + s) * DV + t] = a0;
    }
}

// ---------------------------------------------------------------------------
// Kernel 2: reduce the valid segments per batch; len==0 -> 0.
// Grid (B, DV/64) x 64 threads. Reads only slots kernel1 wrote this call
// (s < nseg, same formula from the same `lengths`).
// ---------------------------------------------------------------------------
__global__ void feasel_reduce_kernel(const float* __restrict__ part,
                                     const int* __restrict__ lengths,
                                     float* __restrict__ out,
                                     int L, int DV, int seg, int S) {
    const int b = blockIdx.x;
    const int c = blockIdx.y * 64 + threadIdx.x;
    if (c >= DV) return;

    int len = lengths[b];
    len = len < 0 ? 0 : (len > L ? L : len);
    int nseg = (len + seg - 1) / seg;
    if (nseg > S) nseg = S;

    f32x4 acc;
    if (len <= 0) {
        f32x4 z = {0.f, 0.f, 0.f, 0.f};
        acc = z;
    } else {
        const f32x4* __restrict__ p =
            reinterpret_cast<const f32x4*>(part) + (size_t)b * S * DV + c;
        f32x4 a0 = fillv4(), a1 = fillv4(), a2 = fillv4(), a3 = fillv4();
        int s = 0;
        for (; s + 4 <= nseg; s += 4) {
            a0 = vmax4(a0, p[(size_t)(s + 0) * DV]);
            a1 = vmax4(a1, p[(size_t)(s + 1) * DV]);
            a2 = vmax4(a2, p[(size_t)(s + 2) * DV]);
            a3 = vmax4(a3, p[(size_t)(s + 3) * DV]);
        }
        for (; s < nseg; ++s)
            a0 = vmax4(a0, p[(size_t)s * DV]);
        acc = vmax4(vmax4(a0, a1), vmax4(a2, a3));
    }
    reinterpret_cast<f32x4*>(out)[(size_t)b * DV + c] = acc;
}

// ---------------------------------------------------------------------------
// Fallback (tiny ws or B > 1024): one block per batch, direct reduction.
// ---------------------------------------------------------------------------
__global__ void feasel_direct_kernel(const float* __restrict__ feat,
                                     const int* __restrict__ lengths,
                                     float* __restrict__ out,
                                     int L, int DV) {
    const int b = blockIdx.x;
    const int t = threadIdx.x;
    int len = lengths[b];
    len = len < 0 ? 0 : (len > L ? L : len);

    const f32x4* __restrict__ p =
        reinterpret_cast<const f32x4*>(feat) + (size_t)b * L * DV + t;

    f32x4 a0 = fillv4(), a1 = fillv4(), a2 = fillv4(), a3 = fillv4();
    int l = 0;
    for (; l + 4 <= len; l += 4) {
        a0 = vmax4(a0, ntload(p + 0 * (size_t)DV));
        a1 = vmax4(a1, ntload(p + 1 * (size_t)DV));
        a2 = vmax4(a2, ntload(p + 2 * (size_t)DV));
        a3 = vmax4(a3, ntload(p + 3 * (size_t)DV));
        p += 4 * (size_t)DV;
    }
    for (; l < len; ++l) {
        a0 = vmax4(a0, ntload(p));
        p += DV;
    }
    a0 = vmax4(vmax4(a0, a1), vmax4(a2, a3));
    if (len <= 0) {
        f32x4 z = {0.f, 0.f, 0.f, 0.f};
        a0 = z;
    }
    reinterpret_cast<f32x4*>(out)[(size_t)b * DV + t] = a0;
}

extern "C" void kernel_launch(void* const* d_in, const int* in_sizes, int n_in,
                              void* d_out, int out_size, void* d_ws, size_t ws_size,
                              hipStream_t stream) {
    const float* feat    = (const float*)d_in[0];   // [B, L, D] fp32
    const int*   lengths = (const int*)d_in[1];     // [B] int32
    float*       out     = (float*)d_out;           // [B, D] fp32

    const int B  = in_sizes[1];
    const int D  = out_size / B;                    // 1024
    const int DV = D / 4;                           // 256 float4 per row
    const int L  = in_sizes[0] / (B * D);           // 4096

    // Segments per batch: largest power of two <= 128 whose partial buffer fits ws.
    int S = 128;
    while (S > 1 && (size_t)B * S * D * sizeof(float) > ws_size) S >>= 1;

    if ((size_t)B * S * D * sizeof(float) <= ws_size && B <= 1024) {
        float* part   = (float*)d_ws;
        const int seg = (L + S - 1) / S;

        feasel_partial_kernel<<<1024, 256, 0, stream>>>(feat, lengths, part,
                                                        B, L, DV, seg, S);

        dim3 grid2(B, (DV + 63) / 64);
        feasel_reduce_kernel<<<grid2, 64, 0, stream>>>(part, lengths, out, L, DV, seg, S);
    } else {
        feasel_direct_kernel<<<B, DV, 0, stream>>>(feat, lengths, out, L, DV);
    }
}